// Round 24
// baseline (158.305 us; speedup 1.0000x reference)
//
#include <hip/hip_runtime.h>
#include <math.h>

#define N_NODES 50000
#define N_EDGES 800000
#define DIN 64
#define HC 256      // H*C
#define NH 4        // heads
#define CPH 64      // channels per head
#define ED 11
#define NPAD 50176  // 196*256
#define NB_SCAN 196
#define NTILE 3125       // N_NODES/16
#define SCAT_BLKS 3125   // N_EDGES/256
#define PROJ_BLKS 782    // ceil(NTILE/4)
#define FOLD_THREADS 45056

typedef unsigned int uint;
typedef unsigned short ushort_t;
using short8 = __attribute__((ext_vector_type(8))) short;
using f32x4  = __attribute__((ext_vector_type(4))) float;

__device__ __forceinline__ ushort_t f2bf(float f) {
    uint u = __float_as_uint(f);
    u = (u + 0x7FFFu + ((u >> 16) & 1u)) >> 16;   // RTNE
    return (ushort_t)u;
}
__device__ __forceinline__ float bf2f(ushort_t h) {
    return __uint_as_float(((uint)h) << 16);
}

// ---------------------------------------------------------------------------
// prep_hist: weight folds into bf16 MFMA B-fragments + dst-degree histogram
// that also records each edge's slot (epos[e]) so the scatter needs no atomic.
__global__ void prep_hist(const float* __restrict__ Wq, const float* __restrict__ Wk,
                          const float* __restrict__ Wv, const float* __restrict__ We,
                          const float* __restrict__ Wskip, const float* __restrict__ Wlin,
                          ushort_t* __restrict__ NPB, ushort_t* __restrict__ WFB,
                          const int* __restrict__ dst, int* __restrict__ deg,
                          int* __restrict__ epos) {
    const int g = blockIdx.x * 256 + threadIdx.x;
    if (g < 16384) {                       // NPB cols 0..255 (G)
        const int d = g >> 8, hc = g & 255;
        const int hb = hc & 192, dp = hc & 63;
        const float* bq = Wq + d * HC + hb;
        const float* bk = Wk + dp * HC + hb;
        float v = 0.f;
        #pragma unroll 8
        for (int c = 0; c < 64; ++c) v = fmaf(bq[c], bk[c], v);
        const int l = (hc & 15) | (((d >> 3) & 3) << 4);
        NPB[(((hc >> 4) * 2 + (d >> 5)) * 64 + l) * 8 + (d & 7)] = f2bf(v);
    } else if (g < 20480) {                // NPB cols 256..319 (QWE fold, padded)
        const int gm = g - 16384;
        const int d = gm >> 6, cm = gm & 63;
        const int h = cm >> 4, jj = cm & 15;
        float v = 0.f;
        if (jj < ED) {
            const float* wq = Wq + d * HC + h * 64;
            const float* we = We + jj * HC + h * 64;
            #pragma unroll 8
            for (int c = 0; c < 64; ++c) v = fmaf(wq[c], we[c], v);
        }
        const int col = 256 + cm;
        const int l = (cm & 15) | (((d >> 3) & 3) << 4);
        NPB[(((col >> 4) * 2 + (d >> 5)) * 64 + l) * 8 + (d & 7)] = f2bf(v);
    } else if (g < 20480 + 24576) {        // WFB: (k<384, o<64)
        const int gm = g - 20480;
        const int k = gm >> 6, o = gm & 63;
        float v = 0.f;
        if (k < 256) {
            const int h = k >> 6, d = k & 63;
            const float* wv = Wv + d * HC + h * 64;
            const float* wl = Wlin + (h * 64) * CPH + o;
            #pragma unroll 8
            for (int c = 0; c < 64; ++c) v = fmaf(wv[c], wl[(size_t)c * CPH], v);
        } else if (k < 320) {
            const int d = k - 256;
            const float* wsk = Wskip + d * HC;
            const float* wl = Wlin + o;
            #pragma unroll 8
            for (int k2 = 0; k2 < 256; ++k2) v = fmaf(wsk[k2], wl[(size_t)k2 * CPH], v);
        } else if (k < 364) {
            const int r = k - 320;
            const int h = r / 11, j = r - h * 11;
            const float* we = We + j * HC + h * 64;
            const float* wl = Wlin + (h * 64) * CPH + o;
            #pragma unroll 8
            for (int c = 0; c < 64; ++c) v = fmaf(we[c], wl[(size_t)c * CPH], v);
        }
        const int l = (o & 15) | (((k >> 3) & 3) << 4);
        WFB[(((k >> 5) * 4 + (o >> 4)) * 64 + l) * 8 + (k & 7)] = f2bf(v);
    } else {                               // histogram + slot assignment
        const int e = g - FOLD_THREADS;
        if (e < N_EDGES) epos[e] = atomicAdd(&deg[dst[e]], 1);
    }
}

// ---------------------------------------------------------------------------
// CSR scans.
__global__ void scan_local(const int* __restrict__ deg, int* __restrict__ rowstart,
                           int* __restrict__ psum) {
    __shared__ int s[256];
    const int b = blockIdx.x, t = threadIdx.x, i = b * 256 + t;
    const int v = (i < N_NODES) ? deg[i] : 0;
    s[t] = v;
    __syncthreads();
    for (int off = 1; off < 256; off <<= 1) {
        const int xr = (t >= off) ? s[t - off] : 0;
        __syncthreads();
        s[t] += xr;
        __syncthreads();
    }
    if (i < N_NODES) rowstart[i] = s[t] - v;  // exclusive within block
    if (t == 255) psum[b] = s[255];
}

__global__ void scan_add(int* __restrict__ rowstart, const int* __restrict__ psum) {
    __shared__ int s[256];
    __shared__ int ex[256];
    const int b = blockIdx.x, t = threadIdx.x;
    const int v = (t < NB_SCAN) ? psum[t] : 0;
    s[t] = v;
    __syncthreads();
    for (int off = 1; off < 256; off <<= 1) {
        const int xr = (t >= off) ? s[t - off] : 0;
        __syncthreads();
        s[t] += xr;
        __syncthreads();
    }
    ex[t] = s[t] - v;   // exclusive
    __syncthreads();
    const int i = b * 256 + t;
    if (i < N_NODES) rowstart[i] += ex[b];
}

// ---------------------------------------------------------------------------
// scatter_proj: FUSED edge scatter (no atomics) + MFMA node projection.
__global__ void __launch_bounds__(256) scatter_proj(
        const int* __restrict__ src, const int* __restrict__ dst,
        const float* __restrict__ ea,
        const int* __restrict__ rowstart, const int* __restrict__ epos,
        uint* __restrict__ EREC,
        const float* __restrict__ x,
        const ushort_t* __restrict__ NPB,
        ushort_t* __restrict__ PB,
        ushort_t* __restrict__ xb) {
    const int bid = blockIdx.x;
    const int t = threadIdx.x;
    if (bid < SCAT_BLKS) {
        // ---- scatter: 32B records [bf16 ea[11], pad0, int src, pad0] ----
        const int e = bid * 256 + t;
        const size_t idx = (size_t)rowstart[dst[e]] + epos[e];
        const float* in = ea + (size_t)e * ED;
        uint w[8];
        #pragma unroll
        for (int jj = 0; jj < 5; ++jj)
            w[jj] = (uint)f2bf(in[2 * jj]) | ((uint)f2bf(in[2 * jj + 1]) << 16);
        w[5] = (uint)f2bf(in[10]);
        w[6] = (uint)src[e];
        w[7] = 0u;
        uint4* o = (uint4*)(EREC + idx * 8);
        o[0] = make_uint4(w[0], w[1], w[2], w[3]);
        o[1] = make_uint4(w[4], w[5], w[6], w[7]);
        return;
    }
    // ---- node projection: PB[n][320] = bf16(x@[G|M2]), xb = bf16(x) ----
    const int lane = t & 63;
    const int tile = (bid - SCAT_BLKS) * 4 + (t >> 6);
    if (tile >= NTILE) return;
    const int n0 = tile * 16;
    const int m = lane & 15, kb = (lane >> 4) * 8;

    short8 a[2];
    #pragma unroll
    for (int ks = 0; ks < 2; ++ks) {
        const float* px = x + (size_t)(n0 + m) * DIN + ks * 32 + kb;
        const float4 u = *(const float4*)px;
        const float4 w4 = *(const float4*)(px + 4);
        short8 av;
        av[0] = (short)f2bf(u.x); av[1] = (short)f2bf(u.y);
        av[2] = (short)f2bf(u.z); av[3] = (short)f2bf(u.w);
        av[4] = (short)f2bf(w4.x); av[5] = (short)f2bf(w4.y);
        av[6] = (short)f2bf(w4.z); av[7] = (short)f2bf(w4.w);
        a[ks] = av;
        *(short8*)(xb + (size_t)(n0 + m) * DIN + ks * 32 + kb) = av;
    }

    const short8* NB = (const short8*)NPB;
    const int rw = (lane >> 4) * 4, cc = lane & 15;

    #pragma unroll
    for (int ct = 0; ct < 20; ++ct) {
        f32x4 c = {0.f, 0.f, 0.f, 0.f};
        c = __builtin_amdgcn_mfma_f32_16x16x32_bf16(a[0], NB[(ct * 2 + 0) * 64 + lane], c, 0, 0, 0);
        c = __builtin_amdgcn_mfma_f32_16x16x32_bf16(a[1], NB[(ct * 2 + 1) * 64 + lane], c, 0, 0, 0);
        #pragma unroll
        for (int r = 0; r < 4; ++r)
            PB[(size_t)(n0 + rw + r) * 320 + ct * 16 + cc] = f2bf(c[r]);
    }
}

// ---------------------------------------------------------------------------
// K2 (MFMA attention, 1 wave = 1 workgroup = 1 dst node): chunks of 16
// edges; 3 MFMAs compute alpha[16e][4h] = [x_src|ea|0] @ [P_h|QWE_h|0]
// (K=96); masked exp on D lanes. x/ea tiles staged in LDS as **f32**
// (bf16->f32 cvt done ONCE at stage time — occupancy is WG-slot capped,
// so the extra LDS is free, unlike the round-21 4-wave regime).
// All MFMA A elements are FINITE bf16 (0*NaN=NaN hazard avoided).
__global__ void __launch_bounds__(64) attnM1f(const uint* __restrict__ EREC,
                      const ushort_t* __restrict__ PB,
                      const ushort_t* __restrict__ xb,
                      const int* __restrict__ rowstart,
                      const int* __restrict__ deg,
                      ushort_t* __restrict__ AROW) {
    __shared__ float XTF[16][68];    // x tile f32, pad 64->68 (4352 B)
    __shared__ float EATF[16][12];   // ea tile f32 (768 B)
    __shared__ float EXS[4][16];     // ex[h][e] (256 B)
    const int lane = threadIdx.x;
    const int n = blockIdx.x;
    const int q = lane >> 4;              // k-octet (MFMA) / head (PV)
    const int e = lane & 15;              // A-row,B-col (MFMA) / slot j (PV)
    const int h = q, j = e;

    const int beg = __builtin_amdgcn_readfirstlane(rowstart[n]);
    const int dc  = __builtin_amdgcn_readfirstlane(deg[n]);

    // B fragments (per node): cols 0..3 = heads, rest zero.
    const ushort_t* pb = PB + (size_t)n * 320;
    short8 b0 = {0,0,0,0,0,0,0,0}, b1 = b0, b2 = b0;
    if (e < 4) {
        b0 = *(const short8*)(pb + e * 64 + q * 8);
        b1 = *(const short8*)(pb + e * 64 + 32 + q * 8);
        if (q < 2) b2 = *(const short8*)(pb + 256 + e * 16 + q * 8);
    }

    float4 acc = {0.f, 0.f, 0.f, 0.f};
    float den = 0.f, Tacc = 0.f;

    for (int cbase = 0; cbase < dc; cbase += 16) {
        const int g = cbase + e;
        const int idx = beg + ((g < dc) ? g : 0);       // clamp: masked later
        const uint* rec = EREC + (size_t)idx * 8;
        const int s = (int)rec[6];
        const ushort_t* xr = xb + (size_t)s * DIN;
        const short8 a0 = *(const short8*)(xr + q * 8);          // k 0..31
        const short8 a1 = *(const short8*)(xr + 32 + q * 8);     // k 32..63

        // k 64..95: [ea0..ea10 | 0...]; build with explicit zeros (finite bf16)
        short8 a2 = {0, 0, 0, 0, 0, 0, 0, 0};
        if (q == 0) {
            a2 = *(const short8*)((const ushort_t*)rec);         // ea0..ea7
        } else if (q == 1) {
            const ushort4 t4 = *(const ushort4*)((const ushort_t*)rec + 8);  // ea8,ea9,ea10,0
            a2[0] = (short)t4.x; a2[1] = (short)t4.y;
            a2[2] = (short)t4.z; a2[3] = (short)t4.w;
        }

        // stage as f32 (convert once)
        {
            float4 f;
            f.x = bf2f((ushort_t)a0[0]); f.y = bf2f((ushort_t)a0[1]);
            f.z = bf2f((ushort_t)a0[2]); f.w = bf2f((ushort_t)a0[3]);
            *(float4*)(&XTF[e][q * 8]) = f;
            f.x = bf2f((ushort_t)a0[4]); f.y = bf2f((ushort_t)a0[5]);
            f.z = bf2f((ushort_t)a0[6]); f.w = bf2f((ushort_t)a0[7]);
            *(float4*)(&XTF[e][q * 8 + 4]) = f;
            f.x = bf2f((ushort_t)a1[0]); f.y = bf2f((ushort_t)a1[1]);
            f.z = bf2f((ushort_t)a1[2]); f.w = bf2f((ushort_t)a1[3]);
            *(float4*)(&XTF[e][32 + q * 8]) = f;
            f.x = bf2f((ushort_t)a1[4]); f.y = bf2f((ushort_t)a1[5]);
            f.z = bf2f((ushort_t)a1[6]); f.w = bf2f((ushort_t)a1[7]);
            *(float4*)(&XTF[e][32 + q * 8 + 4]) = f;
        }
        if (q == 0) {
            float4 f;
            f.x = bf2f((ushort_t)a2[0]); f.y = bf2f((ushort_t)a2[1]);
            f.z = bf2f((ushort_t)a2[2]); f.w = bf2f((ushort_t)a2[3]);
            *(float4*)(&EATF[e][0]) = f;
            f.x = bf2f((ushort_t)a2[4]); f.y = bf2f((ushort_t)a2[5]);
            f.z = bf2f((ushort_t)a2[6]); f.w = bf2f((ushort_t)a2[7]);
            *(float4*)(&EATF[e][4]) = f;
        } else if (q == 1) {
            float4 f;
            f.x = bf2f((ushort_t)a2[0]); f.y = bf2f((ushort_t)a2[1]);
            f.z = bf2f((ushort_t)a2[2]); f.w = bf2f((ushort_t)a2[3]);
            *(float4*)(&EATF[e][8]) = f;
        }

        f32x4 al = {0.f, 0.f, 0.f, 0.f};
        al = __builtin_amdgcn_mfma_f32_16x16x32_bf16(a0, b0, al, 0, 0, 0);
        al = __builtin_amdgcn_mfma_f32_16x16x32_bf16(a1, b1, al, 0, 0, 0);
        al = __builtin_amdgcn_mfma_f32_16x16x32_bf16(a2, b2, al, 0, 0, 0);

        if (e < 4) {   // D cols 0..3 hold heads; rows = q*4+r
            #pragma unroll
            for (int r = 0; r < 4; ++r) {
                const int er = q * 4 + r;
                EXS[e][er] = (cbase + er < dc) ? __expf(al[r] * 0.125f) : 0.f;
            }
        }
        asm volatile("s_waitcnt lgkmcnt(0)" ::: "memory");  // same-wave LDS fence

        const f32x4 x0 = *(const f32x4*)(&EXS[h][0]);
        const f32x4 x1 = *(const f32x4*)(&EXS[h][4]);
        const f32x4 x2 = *(const f32x4*)(&EXS[h][8]);
        const f32x4 x3 = *(const f32x4*)(&EXS[h][12]);
        const float exs[16] = {x0[0],x0[1],x0[2],x0[3], x1[0],x1[1],x1[2],x1[3],
                               x2[0],x2[1],x2[2],x2[3], x3[0],x3[1],x3[2],x3[3]};
        #pragma unroll
        for (int ee = 0; ee < 16; ++ee) {
            const float ex = exs[ee];
            const float4 xv = *(const float4*)(&XTF[ee][j * 4]);
            acc.x = fmaf(ex, xv.x, acc.x);
            acc.y = fmaf(ex, xv.y, acc.y);
            acc.z = fmaf(ex, xv.z, acc.z);
            acc.w = fmaf(ex, xv.w, acc.w);
            den += ex;
            const float eaj = (j < ED) ? EATF[ee][j] : 0.f;
            Tacc = fmaf(ex, eaj, Tacc);
        }
    }

    const float inv = (den > 0.f) ? 1.f / den : 0.f;
    ushort_t* arow = AROW + (size_t)n * 384;
    ushort4 ob;
    ob.x = f2bf(acc.x * inv); ob.y = f2bf(acc.y * inv);
    ob.z = f2bf(acc.z * inv); ob.w = f2bf(acc.w * inv);
    *(ushort4*)(arow + lane * 4) = ob;                    // xagg segment
    if (lane < 8) {                                       // x segment (bf16 x copy)
        const uint4 v = *(const uint4*)(xb + (size_t)n * DIN + lane * 8);
        *(uint4*)(arow + 256 + lane * 8) = v;
    }
    if (j < ED) arow[320 + h * 11 + j] = f2bf(Tacc * inv);  // TO segment
    if (lane >= 44) arow[320 + lane] = 0;                   // pad 364..383
}

// ---------------------------------------------------------------------------
// K3 (MFMA): y = AROW @ WFT (K=384, N=64). 1 wave = 16 nodes.
__global__ void __launch_bounds__(64) finalizeM(const ushort_t* __restrict__ AROW,
                                                const ushort_t* __restrict__ WFB,
                                                float* __restrict__ y) {
    const int lane = threadIdx.x;
    const int n0 = blockIdx.x * 16;
    const int m = lane & 15, kb = (lane >> 4) * 8;
    const short8* WB = (const short8*)WFB;

    f32x4 a0 = {0.f, 0.f, 0.f, 0.f}, a1 = a0, a2 = a0, a3 = a0;
    #pragma unroll
    for (int ks = 0; ks < 12; ++ks) {
        const short8 av = *(const short8*)(AROW + (size_t)(n0 + m) * 384 + ks * 32 + kb);
        a0 = __builtin_amdgcn_mfma_f32_16x16x32_bf16(av, WB[(ks * 4 + 0) * 64 + lane], a0, 0, 0, 0);
        a1 = __builtin_amdgcn_mfma_f32_16x16x32_bf16(av, WB[(ks * 4 + 1) * 64 + lane], a1, 0, 0, 0);
        a2 = __builtin_amdgcn_mfma_f32_16x16x32_bf16(av, WB[(ks * 4 + 2) * 64 + lane], a2, 0, 0, 0);
        a3 = __builtin_amdgcn_mfma_f32_16x16x32_bf16(av, WB[(ks * 4 + 3) * 64 + lane], a3, 0, 0, 0);
    }
    const int rw = (lane >> 4) * 4, cc = lane & 15;
    #pragma unroll
    for (int r = 0; r < 4; ++r) {
        float* yr = y + (size_t)(n0 + rw + r) * CPH + cc;
        yr[0]  = a0[r];
        yr[16] = a1[r];
        yr[32] = a2[r];
        yr[48] = a3[r];
    }
}

// ---------------------------------------------------------------------------
extern "C" void kernel_launch(void* const* d_in, const int* in_sizes, int n_in,
                              void* d_out, int out_size, void* d_ws, size_t ws_size,
                              hipStream_t stream) {
    const float* x     = (const float*)d_in[0];
    const float* ea    = (const float*)d_in[1];
    const int*   eidx  = (const int*)  d_in[2];
    const float* Wq    = (const float*)d_in[3];
    const float* Wk    = (const float*)d_in[4];
    const float* Wv    = (const float*)d_in[5];
    const float* We    = (const float*)d_in[6];
    const float* Wskip = (const float*)d_in[7];
    const float* Wlin  = (const float*)d_in[8];
    float* out = (float*)d_out;

    ushort_t* NPB  = (ushort_t*)d_ws;               // 20480 sh
    ushort_t* WFB  = NPB + 20480;                   // 24576 sh
    ushort_t* PB   = WFB + 24576;                   // N*320 sh
    ushort_t* AROW = PB + (size_t)N_NODES * 320;    // N*384 sh
    ushort_t* xb   = AROW + (size_t)N_NODES * 384;  // N*64 sh
    int* deg     = (int*)(xb + (size_t)N_NODES * DIN);  // NPAD (memset to 0)
    int* rowstart= deg + NPAD;                      // NPAD
    int* psum    = rowstart + NPAD;                 // 256
    int* epos    = psum + 256;                      // E
    uint* EREC   = (uint*)(epos + N_EDGES);         // E*32B

    const int* src = eidx;
    const int* dst = eidx + N_EDGES;

    hipMemsetAsync(deg, 0, (size_t)NPAD * sizeof(int), stream);
    prep_hist<<<(FOLD_THREADS + N_EDGES + 255) / 256, 256, 0, stream>>>(
        Wq, Wk, Wv, We, Wskip, Wlin, NPB, WFB, dst, deg, epos);
    scan_local<<<NB_SCAN, 256, 0, stream>>>(deg, rowstart, psum);
    scan_add<<<NB_SCAN, 256, 0, stream>>>(rowstart, psum);
    scatter_proj<<<SCAT_BLKS + PROJ_BLKS, 256, 0, stream>>>(
        src, dst, ea, rowstart, epos, EREC, x, NPB, PB, xb);
    attnM1f<<<N_NODES, 64, 0, stream>>>(EREC, PB, xb, rowstart, deg, AROW);
    finalizeM<<<N_NODES / 16, 64, 0, stream>>>(AROW, WFB, out);
}

// Round 25
// 154.104 us; speedup vs baseline: 1.0273x; 1.0273x over previous
//
#include <hip/hip_runtime.h>
#include <math.h>

#define N_NODES 50000
#define N_EDGES 800000
#define DIN 64
#define HC 256      // H*C
#define NH 4        // heads
#define CPH 64      // channels per head
#define ED 11
#define NPAD 50176  // 196*256
#define NB_SCAN 196
#define NTILE 3125       // N_NODES/16
#define SCAT_BLKS 3125   // N_EDGES/256
#define PROJ_BLKS 782    // ceil(NTILE/4)
#define FOLD_THREADS 45056

typedef unsigned int uint;
typedef unsigned short ushort_t;
using short8 = __attribute__((ext_vector_type(8))) short;
using f32x4  = __attribute__((ext_vector_type(4))) float;

__device__ __forceinline__ ushort_t f2bf(float f) {
    uint u = __float_as_uint(f);
    u = (u + 0x7FFFu + ((u >> 16) & 1u)) >> 16;   // RTNE
    return (ushort_t)u;
}
__device__ __forceinline__ float bf2f(ushort_t h) {
    return __uint_as_float(((uint)h) << 16);
}

// ---------------------------------------------------------------------------
// prep_hist: weight folds into bf16 MFMA B-fragments + dst-degree histogram
// that also records each edge's slot (epos[e]) so the scatter needs no atomic.
__global__ void prep_hist(const float* __restrict__ Wq, const float* __restrict__ Wk,
                          const float* __restrict__ Wv, const float* __restrict__ We,
                          const float* __restrict__ Wskip, const float* __restrict__ Wlin,
                          ushort_t* __restrict__ NPB, ushort_t* __restrict__ WFB,
                          const int* __restrict__ dst, int* __restrict__ deg,
                          int* __restrict__ epos) {
    const int g = blockIdx.x * 256 + threadIdx.x;
    if (g < 16384) {                       // NPB cols 0..255 (G)
        const int d = g >> 8, hc = g & 255;
        const int hb = hc & 192, dp = hc & 63;
        const float* bq = Wq + d * HC + hb;
        const float* bk = Wk + dp * HC + hb;
        float v = 0.f;
        #pragma unroll 8
        for (int c = 0; c < 64; ++c) v = fmaf(bq[c], bk[c], v);
        const int l = (hc & 15) | (((d >> 3) & 3) << 4);
        NPB[(((hc >> 4) * 2 + (d >> 5)) * 64 + l) * 8 + (d & 7)] = f2bf(v);
    } else if (g < 20480) {                // NPB cols 256..319 (QWE fold, padded)
        const int gm = g - 16384;
        const int d = gm >> 6, cm = gm & 63;
        const int h = cm >> 4, jj = cm & 15;
        float v = 0.f;
        if (jj < ED) {
            const float* wq = Wq + d * HC + h * 64;
            const float* we = We + jj * HC + h * 64;
            #pragma unroll 8
            for (int c = 0; c < 64; ++c) v = fmaf(wq[c], we[c], v);
        }
        const int col = 256 + cm;
        const int l = (cm & 15) | (((d >> 3) & 3) << 4);
        NPB[(((col >> 4) * 2 + (d >> 5)) * 64 + l) * 8 + (d & 7)] = f2bf(v);
    } else if (g < 20480 + 24576) {        // WFB: (k<384, o<64)
        const int gm = g - 20480;
        const int k = gm >> 6, o = gm & 63;
        float v = 0.f;
        if (k < 256) {
            const int h = k >> 6, d = k & 63;
            const float* wv = Wv + d * HC + h * 64;
            const float* wl = Wlin + (h * 64) * CPH + o;
            #pragma unroll 8
            for (int c = 0; c < 64; ++c) v = fmaf(wv[c], wl[(size_t)c * CPH], v);
        } else if (k < 320) {
            const int d = k - 256;
            const float* wsk = Wskip + d * HC;
            const float* wl = Wlin + o;
            #pragma unroll 8
            for (int k2 = 0; k2 < 256; ++k2) v = fmaf(wsk[k2], wl[(size_t)k2 * CPH], v);
        } else if (k < 364) {
            const int r = k - 320;
            const int h = r / 11, j = r - h * 11;
            const float* we = We + j * HC + h * 64;
            const float* wl = Wlin + (h * 64) * CPH + o;
            #pragma unroll 8
            for (int c = 0; c < 64; ++c) v = fmaf(we[c], wl[(size_t)c * CPH], v);
        }
        const int l = (o & 15) | (((k >> 3) & 3) << 4);
        WFB[(((k >> 5) * 4 + (o >> 4)) * 64 + l) * 8 + (k & 7)] = f2bf(v);
    } else {                               // histogram + slot assignment
        const int e = g - FOLD_THREADS;
        if (e < N_EDGES) epos[e] = atomicAdd(&deg[dst[e]], 1);
    }
}

// ---------------------------------------------------------------------------
// CSR scans.
__global__ void scan_local(const int* __restrict__ deg, int* __restrict__ rowstart,
                           int* __restrict__ psum) {
    __shared__ int s[256];
    const int b = blockIdx.x, t = threadIdx.x, i = b * 256 + t;
    const int v = (i < N_NODES) ? deg[i] : 0;
    s[t] = v;
    __syncthreads();
    for (int off = 1; off < 256; off <<= 1) {
        const int xr = (t >= off) ? s[t - off] : 0;
        __syncthreads();
        s[t] += xr;
        __syncthreads();
    }
    if (i < N_NODES) rowstart[i] = s[t] - v;  // exclusive within block
    if (t == 255) psum[b] = s[255];
}

__global__ void scan_add(int* __restrict__ rowstart, const int* __restrict__ psum) {
    __shared__ int s[256];
    __shared__ int ex[256];
    const int b = blockIdx.x, t = threadIdx.x;
    const int v = (t < NB_SCAN) ? psum[t] : 0;
    s[t] = v;
    __syncthreads();
    for (int off = 1; off < 256; off <<= 1) {
        const int xr = (t >= off) ? s[t - off] : 0;
        __syncthreads();
        s[t] += xr;
        __syncthreads();
    }
    ex[t] = s[t] - v;   // exclusive
    __syncthreads();
    const int i = b * 256 + t;
    if (i < N_NODES) rowstart[i] += ex[b];
}

// ---------------------------------------------------------------------------
// scatter_proj: FUSED edge scatter (no atomics) + MFMA node projection.
__global__ void __launch_bounds__(256) scatter_proj(
        const int* __restrict__ src, const int* __restrict__ dst,
        const float* __restrict__ ea,
        const int* __restrict__ rowstart, const int* __restrict__ epos,
        uint* __restrict__ EREC,
        const float* __restrict__ x,
        const ushort_t* __restrict__ NPB,
        ushort_t* __restrict__ PB,
        ushort_t* __restrict__ xb) {
    const int bid = blockIdx.x;
    const int t = threadIdx.x;
    if (bid < SCAT_BLKS) {
        // ---- scatter: 32B records [bf16 ea[11], pad0, int src, pad0] ----
        const int e = bid * 256 + t;
        const size_t idx = (size_t)rowstart[dst[e]] + epos[e];
        const float* in = ea + (size_t)e * ED;
        uint w[8];
        #pragma unroll
        for (int jj = 0; jj < 5; ++jj)
            w[jj] = (uint)f2bf(in[2 * jj]) | ((uint)f2bf(in[2 * jj + 1]) << 16);
        w[5] = (uint)f2bf(in[10]);
        w[6] = (uint)src[e];
        w[7] = 0u;
        uint4* o = (uint4*)(EREC + idx * 8);
        o[0] = make_uint4(w[0], w[1], w[2], w[3]);
        o[1] = make_uint4(w[4], w[5], w[6], w[7]);
        return;
    }
    // ---- node projection: PB[n][320] = bf16(x@[G|M2]), xb = bf16(x) ----
    const int lane = t & 63;
    const int tile = (bid - SCAT_BLKS) * 4 + (t >> 6);
    if (tile >= NTILE) return;
    const int n0 = tile * 16;
    const int m = lane & 15, kb = (lane >> 4) * 8;

    short8 a[2];
    #pragma unroll
    for (int ks = 0; ks < 2; ++ks) {
        const float* px = x + (size_t)(n0 + m) * DIN + ks * 32 + kb;
        const float4 u = *(const float4*)px;
        const float4 w4 = *(const float4*)(px + 4);
        short8 av;
        av[0] = (short)f2bf(u.x); av[1] = (short)f2bf(u.y);
        av[2] = (short)f2bf(u.z); av[3] = (short)f2bf(u.w);
        av[4] = (short)f2bf(w4.x); av[5] = (short)f2bf(w4.y);
        av[6] = (short)f2bf(w4.z); av[7] = (short)f2bf(w4.w);
        a[ks] = av;
        *(short8*)(xb + (size_t)(n0 + m) * DIN + ks * 32 + kb) = av;
    }

    const short8* NB = (const short8*)NPB;
    const int rw = (lane >> 4) * 4, cc = lane & 15;

    #pragma unroll
    for (int ct = 0; ct < 20; ++ct) {
        f32x4 c = {0.f, 0.f, 0.f, 0.f};
        c = __builtin_amdgcn_mfma_f32_16x16x32_bf16(a[0], NB[(ct * 2 + 0) * 64 + lane], c, 0, 0, 0);
        c = __builtin_amdgcn_mfma_f32_16x16x32_bf16(a[1], NB[(ct * 2 + 1) * 64 + lane], c, 0, 0, 0);
        #pragma unroll
        for (int r = 0; r < 4; ++r)
            PB[(size_t)(n0 + rw + r) * 320 + ct * 16 + cc] = f2bf(c[r]);
    }
}

// ---------------------------------------------------------------------------
// K2 (MFMA attention, 1 wave = 1 workgroup = 1 dst node): chunks of 16
// edges; 3 MFMAs compute alpha[16e][4h] = [x_src|ea|0] @ [P_h|QWE_h|0]
// (K=96); masked exp on D lanes; x/ea tiles in per-WG LDS. Wave-granular
// workgroups eliminate the 4-wave block-retire imbalance (Poisson degrees).
// All A elements are FINITE bf16 (0*NaN=NaN hazard avoided).
__global__ void __launch_bounds__(64) attnM1(const uint* __restrict__ EREC,
                      const ushort_t* __restrict__ PB,
                      const ushort_t* __restrict__ xb,
                      const int* __restrict__ rowstart,
                      const int* __restrict__ deg,
                      ushort_t* __restrict__ AROW) {
    __shared__ ushort_t XT[16][72];    // x tile, pad 64->72 (2304 B)
    __shared__ ushort_t EAT[16][24];   // ea tile, pad 16->24 (768 B)
    __shared__ float    EXS[4][16];    // ex[h][e] (256 B)
    const int lane = threadIdx.x;
    const int n = blockIdx.x;
    const int q = lane >> 4;              // k-octet (MFMA) / head (PV)
    const int e = lane & 15;              // A-row,B-col (MFMA) / slot j (PV)
    const int h = q, j = e;

    const int beg = __builtin_amdgcn_readfirstlane(rowstart[n]);
    const int dc  = __builtin_amdgcn_readfirstlane(deg[n]);

    // B fragments (per node): cols 0..3 = heads, rest zero.
    const ushort_t* pb = PB + (size_t)n * 320;
    short8 b0 = {0,0,0,0,0,0,0,0}, b1 = b0, b2 = b0;
    if (e < 4) {
        b0 = *(const short8*)(pb + e * 64 + q * 8);
        b1 = *(const short8*)(pb + e * 64 + 32 + q * 8);
        if (q < 2) b2 = *(const short8*)(pb + 256 + e * 16 + q * 8);
    }

    float4 acc = {0.f, 0.f, 0.f, 0.f};
    float den = 0.f, Tacc = 0.f;

    for (int cbase = 0; cbase < dc; cbase += 16) {
        const int g = cbase + e;
        const int idx = beg + ((g < dc) ? g : 0);       // clamp: masked later
        const uint* rec = EREC + (size_t)idx * 8;
        const int s = (int)rec[6];
        const ushort_t* xr = xb + (size_t)s * DIN;
        const short8 a0 = *(const short8*)(xr + q * 8);          // k 0..31
        const short8 a1 = *(const short8*)(xr + 32 + q * 8);     // k 32..63

        // k 64..95: [ea0..ea10 | 0...]; build with explicit zeros (finite bf16)
        short8 a2 = {0, 0, 0, 0, 0, 0, 0, 0};
        if (q == 0) {
            a2 = *(const short8*)((const ushort_t*)rec);         // ea0..ea7
        } else if (q == 1) {
            const ushort4 t4 = *(const ushort4*)((const ushort_t*)rec + 8);  // ea8,ea9,ea10,0
            a2[0] = (short)t4.x; a2[1] = (short)t4.y;
            a2[2] = (short)t4.z; a2[3] = (short)t4.w;
        }

        *(short8*)(&XT[e][q * 8]) = a0;
        *(short8*)(&XT[e][32 + q * 8]) = a1;
        if (q < 2) *(short8*)(&EAT[e][q * 8]) = a2;

        f32x4 al = {0.f, 0.f, 0.f, 0.f};
        al = __builtin_amdgcn_mfma_f32_16x16x32_bf16(a0, b0, al, 0, 0, 0);
        al = __builtin_amdgcn_mfma_f32_16x16x32_bf16(a1, b1, al, 0, 0, 0);
        al = __builtin_amdgcn_mfma_f32_16x16x32_bf16(a2, b2, al, 0, 0, 0);

        if (e < 4) {   // D cols 0..3 hold heads; rows = q*4+r
            #pragma unroll
            for (int r = 0; r < 4; ++r) {
                const int er = q * 4 + r;
                EXS[e][er] = (cbase + er < dc) ? __expf(al[r] * 0.125f) : 0.f;
            }
        }
        asm volatile("s_waitcnt lgkmcnt(0)" ::: "memory");  // same-wave LDS fence

        const f32x4 x0 = *(const f32x4*)(&EXS[h][0]);
        const f32x4 x1 = *(const f32x4*)(&EXS[h][4]);
        const f32x4 x2 = *(const f32x4*)(&EXS[h][8]);
        const f32x4 x3 = *(const f32x4*)(&EXS[h][12]);
        const float exs[16] = {x0[0],x0[1],x0[2],x0[3], x1[0],x1[1],x1[2],x1[3],
                               x2[0],x2[1],x2[2],x2[3], x3[0],x3[1],x3[2],x3[3]};
        #pragma unroll
        for (int ee = 0; ee < 16; ++ee) {
            const float ex = exs[ee];
            const ushort4 xv = *(const ushort4*)(&XT[ee][j * 4]);
            acc.x = fmaf(ex, bf2f(xv.x), acc.x);
            acc.y = fmaf(ex, bf2f(xv.y), acc.y);
            acc.z = fmaf(ex, bf2f(xv.z), acc.z);
            acc.w = fmaf(ex, bf2f(xv.w), acc.w);
            den += ex;
            const float eaj = (j < ED) ? bf2f(EAT[ee][j]) : 0.f;
            Tacc = fmaf(ex, eaj, Tacc);
        }
    }

    const float inv = (den > 0.f) ? 1.f / den : 0.f;
    ushort_t* arow = AROW + (size_t)n * 384;
    ushort4 ob;
    ob.x = f2bf(acc.x * inv); ob.y = f2bf(acc.y * inv);
    ob.z = f2bf(acc.z * inv); ob.w = f2bf(acc.w * inv);
    *(ushort4*)(arow + lane * 4) = ob;                    // xagg segment
    if (lane < 8) {                                       // x segment (bf16 x copy)
        const uint4 v = *(const uint4*)(xb + (size_t)n * DIN + lane * 8);
        *(uint4*)(arow + 256 + lane * 8) = v;
    }
    if (j < ED) arow[320 + h * 11 + j] = f2bf(Tacc * inv);  // TO segment
    if (lane >= 44) arow[320 + lane] = 0;                   // pad 364..383
}

// ---------------------------------------------------------------------------
// K3 (MFMA): y = AROW @ WFT (K=384, N=64). 1 wave = 16 nodes.
__global__ void __launch_bounds__(64) finalizeM(const ushort_t* __restrict__ AROW,
                                                const ushort_t* __restrict__ WFB,
                                                float* __restrict__ y) {
    const int lane = threadIdx.x;
    const int n0 = blockIdx.x * 16;
    const int m = lane & 15, kb = (lane >> 4) * 8;
    const short8* WB = (const short8*)WFB;

    f32x4 a0 = {0.f, 0.f, 0.f, 0.f}, a1 = a0, a2 = a0, a3 = a0;
    #pragma unroll
    for (int ks = 0; ks < 12; ++ks) {
        const short8 av = *(const short8*)(AROW + (size_t)(n0 + m) * 384 + ks * 32 + kb);
        a0 = __builtin_amdgcn_mfma_f32_16x16x32_bf16(av, WB[(ks * 4 + 0) * 64 + lane], a0, 0, 0, 0);
        a1 = __builtin_amdgcn_mfma_f32_16x16x32_bf16(av, WB[(ks * 4 + 1) * 64 + lane], a1, 0, 0, 0);
        a2 = __builtin_amdgcn_mfma_f32_16x16x32_bf16(av, WB[(ks * 4 + 2) * 64 + lane], a2, 0, 0, 0);
        a3 = __builtin_amdgcn_mfma_f32_16x16x32_bf16(av, WB[(ks * 4 + 3) * 64 + lane], a3, 0, 0, 0);
    }
    const int rw = (lane >> 4) * 4, cc = lane & 15;
    #pragma unroll
    for (int r = 0; r < 4; ++r) {
        float* yr = y + (size_t)(n0 + rw + r) * CPH + cc;
        yr[0]  = a0[r];
        yr[16] = a1[r];
        yr[32] = a2[r];
        yr[48] = a3[r];
    }
}

// ---------------------------------------------------------------------------
extern "C" void kernel_launch(void* const* d_in, const int* in_sizes, int n_in,
                              void* d_out, int out_size, void* d_ws, size_t ws_size,
                              hipStream_t stream) {
    const float* x     = (const float*)d_in[0];
    const float* ea    = (const float*)d_in[1];
    const int*   eidx  = (const int*)  d_in[2];
    const float* Wq    = (const float*)d_in[3];
    const float* Wk    = (const float*)d_in[4];
    const float* Wv    = (const float*)d_in[5];
    const float* We    = (const float*)d_in[6];
    const float* Wskip = (const float*)d_in[7];
    const float* Wlin  = (const float*)d_in[8];
    float* out = (float*)d_out;

    ushort_t* NPB  = (ushort_t*)d_ws;               // 20480 sh
    ushort_t* WFB  = NPB + 20480;                   // 24576 sh
    ushort_t* PB   = WFB + 24576;                   // N*320 sh
    ushort_t* AROW = PB + (size_t)N_NODES * 320;    // N*384 sh
    ushort_t* xb   = AROW + (size_t)N_NODES * 384;  // N*64 sh
    int* deg     = (int*)(xb + (size_t)N_NODES * DIN);  // NPAD (memset to 0)
    int* rowstart= deg + NPAD;                      // NPAD
    int* psum    = rowstart + NPAD;                 // 256
    int* epos    = psum + 256;                      // E
    uint* EREC   = (uint*)(epos + N_EDGES);         // E*32B

    const int* src = eidx;
    const int* dst = eidx + N_EDGES;

    hipMemsetAsync(deg, 0, (size_t)NPAD * sizeof(int), stream);
    prep_hist<<<(FOLD_THREADS + N_EDGES + 255) / 256, 256, 0, stream>>>(
        Wq, Wk, Wv, We, Wskip, Wlin, NPB, WFB, dst, deg, epos);
    scan_local<<<NB_SCAN, 256, 0, stream>>>(deg, rowstart, psum);
    scan_add<<<NB_SCAN, 256, 0, stream>>>(rowstart, psum);
    scatter_proj<<<SCAT_BLKS + PROJ_BLKS, 256, 0, stream>>>(
        src, dst, ea, rowstart, epos, EREC, x, NPB, PB, xb);
    attnM1<<<N_NODES, 64, 0, stream>>>(EREC, PB, xb, rowstart, deg, AROW);
    finalizeM<<<N_NODES / 16, 64, 0, stream>>>(AROW, WFB, out);
}